// Round 6
// baseline (274.973 us; speedup 1.0000x reference)
//
#include <hip/hip_runtime.h>

typedef unsigned short u16;
typedef unsigned int   u32;
typedef __attribute__((ext_vector_type(8)))  short bf16x8;
typedef __attribute__((ext_vector_type(4)))  float f32x4;
typedef __attribute__((ext_vector_type(4)))  u32   u32x4;

#define BB   2
#define NCH  32
#define DD   64
#define PD   66
#define NTAP 27
#define D3   (DD * DD * DD)

// conv LDS ring: 4 slots, each one z-plane window [q 4][row 6][x 66][16B]
#define RS   (66 * 8)               // row stride, u16
#define QSS  (6 * RS)               // quarter stride, u16
#define PS   (4 * QSS)              // plane (slot) stride, u16 = 12672
// tile = 4 * PS u16 = 101,376 B

__device__ __forceinline__ u16 f2bf(float f) {
  u32 u = __float_as_uint(f);
  u = (u + 0x7fffu + ((u >> 16) & 1u)) >> 16;   // RNE
  return (u16)u;
}

__device__ __forceinline__ void glds16(const u16* g, u16* l) {
  __builtin_amdgcn_global_load_lds(
      (const __attribute__((address_space(1))) u32*)(const void*)g,
      (__attribute__((address_space(3))) u32*)(void*)l, 16, 0, 0);
}

// ---- Kernel 0: pack w1/w2/w3 into 16x16x32 B-fragment layout ---------------
// wb[((tap*3+c)*2+nh)*512 + lane*8 + j] = w_c[o=nh*16+(lane&15)][tap][ci=8*(lane>>4)+j]
__global__ void pack_w_kernel(const float* __restrict__ w1,
                              const float* __restrict__ w2,
                              const float* __restrict__ w3,
                              u16* __restrict__ wb) {
  int i = blockIdx.x * 256 + threadIdx.x;
  if (i >= NTAP * 3 * 2 * 512) return;
  int j    = i & 7;
  int lane = (i >> 3) & 63;
  int nh   = (i >> 9) & 1;
  int q    = i >> 10;            // tap*3 + c
  int c    = q % 3;
  int tap  = q / 3;
  int o  = nh * 16 + (lane & 15);
  int ci = (lane >> 4) * 8 + j;
  const float* ws = (c == 0) ? w1 : (c == 1) ? w2 : w3;
  wb[i] = f2bf(ws[(size_t)o * (NTAP * NCH) + tap * NCH + ci]);
}

// ---- Kernel 1a: zero the halo of xl ---------------------------------------
__global__ void zero_halo_kernel(u16* __restrict__ xl) {
  int tid = blockIdx.x * 256 + threadIdx.x;
  if (tid >= BB * PD * PD * PD) return;
  int xp = tid % PD;
  int t  = tid / PD;
  int yp = t % PD;  t /= PD;
  int zp = t % PD;
  if (xp && yp && zp && xp < PD - 1 && yp < PD - 1 && zp < PD - 1) return;
  u32x4 z4 = {0u, 0u, 0u, 0u};
  u32x4* dst = (u32x4*)(xl + (size_t)tid * NCH);
#pragma unroll
  for (int i = 0; i < 4; i++) dst[i] = z4;
}

// ---- Kernel 1b: interior xl = log(x) -> channels-last bf16 -----------------
__global__ __launch_bounds__(256) void build_xl_kernel(const float* __restrict__ x,
                                                       u16* __restrict__ xl) {
  __shared__ __align__(16) u16 lds[256][40];
  int bi = blockIdx.x;            // b*1024 + z*16 + yt
  int yt = bi & 15;
  int z  = (bi >> 4) & 63;
  int b  = bi >> 10;
  int t  = threadIdx.x;
  int x4 = t & 15, yy = (t >> 4) & 3, c0 = t >> 6;
  int y0 = yt * 4;

  const float* src = x + (size_t)b * NCH * D3 + ((size_t)z * DD + (y0 + yy)) * DD + x4 * 4;
  int v0 = yy * 64 + x4 * 4;
#pragma unroll
  for (int p = 0; p < 8; p++) {
    int c = c0 + 4 * p;
    f32x4 f = *(const f32x4*)(src + (size_t)c * D3);
#pragma unroll
    for (int k = 0; k < 4; k++) lds[v0 + k][c] = f2bf(__logf(f[k]));
  }
  __syncthreads();

  int vy = t >> 6, vx = t & 63;
  u16* dst = xl + ((((size_t)b * PD + (z + 1)) * PD + (y0 + vy + 1)) * PD + (vx + 1)) * NCH;
#pragma unroll
  for (int q = 0; q < 4; q++)
    *(bf16x8*)(dst + q * 8) = *(const bf16x8*)&lds[t][q * 8];
}

// ---- Kernel 2: z-sliding ring-pipelined 27-tap implicit GEMM + epilogue ----
// block = 512 thr / 8 waves = (y-row yy, o-half nh); block tile = 4y x 64x x
// 32o x 8z. LDS ring of 4 z-plane windows; STAGE(z+3) overlaps COMPUTE(z).
__global__ __launch_bounds__(512, 2) void conv_volterra_kernel(
    const u16* __restrict__ xl, const u16* __restrict__ wb,
    const float* __restrict__ x, float* __restrict__ out) {
  __shared__ __align__(16) u16 tile[4 * PS];   // 101,376 B

  // blk = (b*16 + yt)*8 + zc : zc = XCD id -> z-slab L2 affinity
  int i = blockIdx.x;
  int zc = i & 7, r = i >> 3;
  int yt = r & 15;
  int b  = r >> 4;
  int y0 = yt * 4;
  int z0 = zc * 8;

  int tid = threadIdx.x, wv = tid >> 6, lane = tid & 63;
  int l15 = lane & 15, l4 = lane >> 4;
  int yy = wv >> 1, nh = wv & 1;

  const u16* wB = wb + nh * 512 + lane * 8;
  const u16* xlb = xl + (size_t)b * PD * PD * PD * NCH;

  // stage padded plane p (slot p&3): 24 glds (wave wv does q=wv>>1, rows (wv&1)*3+k)
  // + 48-thread tail for x=64,65.
#define STAGE(P)                                                               \
  {                                                                            \
    const int p_ = (P);                                                        \
    u16* dst_ = tile + (p_ & 3) * PS + (wv >> 1) * QSS + ((wv & 1) * 3) * RS;  \
    const u16* src_ = xlb + (((size_t)p_ * PD) + (y0 + (wv & 1) * 3)) * PD * NCH \
                    + lane * NCH + (wv >> 1) * 8;                              \
    _Pragma("unroll")                                                          \
    for (int k_ = 0; k_ < 3; k_++)                                             \
      glds16(src_ + (size_t)k_ * PD * NCH, dst_ + k_ * RS);                    \
    if (tid < 48) {                                                            \
      int q_ = tid & 3, u_ = tid >> 2;                                         \
      int row_ = u_ >> 1, xt_ = 64 + (u_ & 1);                                 \
      u32x4 v_ = *(const u32x4*)(xlb + (((size_t)p_ * PD) + (y0 + row_)) * PD * NCH \
                                 + xt_ * NCH + q_ * 8);                        \
      *(u32x4*)(tile + (p_ & 3) * PS + q_ * QSS + row_ * RS + xt_ * 8) = v_;   \
    }                                                                          \
  }

  STAGE(z0); STAGE(z0 + 1); STAGE(z0 + 2);
  __syncthreads();

#pragma unroll 1
  for (int zi = 0; zi < 8; ++zi) {
    const int z = z0 + zi;
    if (zi < 7) STAGE(z + 3);

    f32x4 acc[3][4];
#pragma unroll
    for (int c = 0; c < 3; c++)
#pragma unroll
      for (int m = 0; m < 4; m++) acc[c][m] = (f32x4){0.f, 0.f, 0.f, 0.f};

#pragma unroll
    for (int kd = 0; kd < 3; ++kd) {
      const u16* Ap = tile + ((z + kd) & 3) * PS + l4 * QSS;
#pragma unroll
      for (int khy = 0; khy < 3; ++khy) {
        const u16* Ar = Ap + (yy + khy) * RS + l15 * 8;
#pragma unroll
        for (int kw = 0; kw < 3; ++kw) {
          const int tap = (kd * 3 + khy) * 3 + kw;
          bf16x8 bwf[3];
#pragma unroll
          for (int c = 0; c < 3; c++)
            bwf[c] = *(const bf16x8*)(wB + (size_t)(tap * 3 + c) * 1024);
          bf16x8 a[4];
#pragma unroll
          for (int m = 0; m < 4; m++)
            a[m] = *(const bf16x8*)(Ar + (m * 16 + kw) * 8);
#pragma unroll
          for (int m = 0; m < 4; m++)
#pragma unroll
            for (int c = 0; c < 3; c++)
              acc[c][m] = __builtin_amdgcn_mfma_f32_16x16x32_bf16(
                  a[m], bwf[c], acc[c][m], 0, 0, 0);
        }
      }
    }

    // fused epilogue: out = x * exp(l1 + l2*l3)
    const int o = nh * 16 + l15;
    const size_t pb = (size_t)(b * NCH + o) * D3 + ((size_t)z * DD + (y0 + yy)) * DD;
#pragma unroll
    for (int m = 0; m < 4; m++) {
      size_t idx = pb + m * 16 + l4 * 4;
      f32x4 xv = *(const f32x4*)(x + idx);
      f32x4 rr;
#pragma unroll
      for (int j = 0; j < 4; j++)
        rr[j] = xv[j] * __expf(acc[0][m][j] + acc[1][m][j] * acc[2][m][j]);
      *(f32x4*)(out + idx) = rr;
    }
    __syncthreads();
  }
#undef STAGE
}

extern "C" void kernel_launch(void* const* d_in, const int* in_sizes, int n_in,
                              void* d_out, int out_size, void* d_ws, size_t ws_size,
                              hipStream_t stream) {
  const float* x  = (const float*)d_in[0];
  const float* w1 = (const float*)d_in[1];
  const float* w2 = (const float*)d_in[2];
  const float* w3 = (const float*)d_in[3];
  float* out = (float*)d_out;
  u16* xl = (u16*)d_ws;                                  // 2*66^3*32 bf16 = 36.8 MB
  u16* wb = xl + (size_t)BB * PD * PD * PD * NCH;        // +166 KB packed weights

  pack_w_kernel<<<(NTAP * 3 * 2 * 512 + 255) / 256, 256, 0, stream>>>(w1, w2, w3, wb);
  const int npad = BB * PD * PD * PD;
  zero_halo_kernel<<<(npad + 255) / 256, 256, 0, stream>>>(xl);
  build_xl_kernel<<<BB * DD * 16, 256, 0, stream>>>(x, xl);
  conv_volterra_kernel<<<256, 512, 0, stream>>>(xl, wb, x, out);
}

// Round 7
// 192.957 us; speedup vs baseline: 1.4251x; 1.4251x over previous
//
#include <hip/hip_runtime.h>

typedef unsigned short u16;
typedef unsigned int   u32;
typedef unsigned long long u64;
typedef __attribute__((ext_vector_type(8)))  short bf16x8;
typedef __attribute__((ext_vector_type(4)))  float f32x4;
typedef __attribute__((ext_vector_type(4)))  u32   u32x4;

#define BB   2
#define NCH  32
#define DD   64
#define PD   66
#define NTAP 27
#define D3   (DD * DD * DD)

// q-planar xl: xlq[q][b][zp][yp][xp][8 u16]
#define PLANE ((size_t)BB * PD * PD * PD * 8)          // u16 per q-plane
#define XOFF(b, zp, yp, xp) \
  (((((size_t)(b) * PD + (zp)) * PD + (yp)) * PD + (xp)) * 8)

// conv LDS tile: [q 4][row 18][x 68][8 u16] (+8 u16 quarter pad) — r4-identical
#define RS   (68 * 8)
#define QS   (18 * RS + 8)

__device__ __forceinline__ u16 f2bf(float f) {
  u32 u = __float_as_uint(f);
  u = (u + 0x7fffu + ((u >> 16) & 1u)) >> 16;   // RNE
  return (u16)u;
}

__device__ __forceinline__ void glds16(const u16* g, u16* l) {
  __builtin_amdgcn_global_load_lds(
      (const __attribute__((address_space(1))) u32*)(const void*)g,
      (__attribute__((address_space(3))) u32*)(void*)l, 16, 0, 0);
}

// ---- Kernel 0: pack w1/w2/w3 into 16x16x32 B-fragment layout ---------------
// wb[((tap*3+c)*2+nh)*512 + lane*8 + j] = w_c[o=nh*16+(lane&15)][tap][ci=8*(lane>>4)+j]
__global__ void pack_w_kernel(const float* __restrict__ w1,
                              const float* __restrict__ w2,
                              const float* __restrict__ w3,
                              u16* __restrict__ wb) {
  int i = blockIdx.x * 256 + threadIdx.x;
  if (i >= NTAP * 3 * 2 * 512) return;
  int j    = i & 7;
  int lane = (i >> 3) & 63;
  int nh   = (i >> 9) & 1;
  int q    = i >> 10;            // tap*3 + c
  int c    = q % 3;
  int tap  = q / 3;
  int o  = nh * 16 + (lane & 15);
  int ci = (lane >> 4) * 8 + j;
  const float* ws = (c == 0) ? w1 : (c == 1) ? w2 : w3;
  wb[i] = f2bf(ws[(size_t)o * (NTAP * NCH) + tap * NCH + ci]);
}

// ---- Kernel 1a: zero the halo of xlq ---------------------------------------
__global__ void zero_halo_kernel(u16* __restrict__ xlq) {
  int tid = blockIdx.x * 256 + threadIdx.x;
  if (tid >= BB * PD * PD * PD) return;
  int xp = tid % PD;
  int t  = tid / PD;
  int yp = t % PD;  t /= PD;
  int zp = t % PD;
  int b  = t / PD;
  if (xp && yp && zp && xp < PD - 1 && yp < PD - 1 && zp < PD - 1) return;
  u32x4 z4 = {0u, 0u, 0u, 0u};
  size_t off = XOFF(b, zp, yp, xp);
#pragma unroll
  for (int q = 0; q < 4; q++)
    *(u32x4*)(xlq + q * PLANE + off) = z4;
}

// ---- Kernel 1b: interior xlq = log(x), q-planar channels-last bf16 ---------
// block = 256 thr = (b, z, 4 y-rows). Phase 1: coalesced f32x4 reads + packed
// u64 LDS-transpose writes (4-way max). Phase 2: word-broadcast u16 reads,
// coalesced 16B global writes per q-plane.
__global__ __launch_bounds__(256) void build_xl_kernel(const float* __restrict__ x,
                                                       u16* __restrict__ xlq) {
  __shared__ u64 ldsT[32][66];   // [c][voxel/4], 16.9 KB
  int bi = blockIdx.x;            // b*1024 + z*16 + yt
  int yt = bi & 15;
  int z  = (bi >> 4) & 63;
  int b  = bi >> 10;
  int t  = threadIdx.x;
  int x4 = t & 15, yy = (t >> 4) & 3, c0 = t >> 6;
  int y0 = yt * 4;

  const float* src = x + (size_t)b * NCH * D3 + ((size_t)z * DD + (y0 + yy)) * DD + x4 * 4;
  int i0 = yy * 16 + x4;
#pragma unroll
  for (int p = 0; p < 8; p++) {
    int c = c0 + 4 * p;           // wave-uniform c
    f32x4 f = *(const f32x4*)(src + (size_t)c * D3);
    u64 pk = (u64)f2bf(__logf(f[0]))
           | ((u64)f2bf(__logf(f[1])) << 16)
           | ((u64)f2bf(__logf(f[2])) << 32)
           | ((u64)f2bf(__logf(f[3])) << 48);
    ldsT[c][i0] = pk;
  }
  __syncthreads();

  // phase 2: thread t -> q = t>>6, voxels m*64 + (t&63), m = 0..3 (m = y-row)
  int q = t >> 6, lv = t & 63;
  const u16* ldsu = (const u16*)ldsT;
#pragma unroll
  for (int m = 0; m < 4; m++) {
    int v = m * 64 + lv;
    int iw = v >> 2, hs = v & 3;
    bf16x8 val;
#pragma unroll
    for (int j = 0; j < 8; j++)
      val[j] = (short)ldsu[((q * 8 + j) * 66 + iw) * 4 + hs];
    *(bf16x8*)(xlq + q * PLANE + XOFF(b, z + 1, y0 + m + 1, lv + 1)) = val;
  }
}

// ---- Kernel 2: LDS-staged 27-tap implicit GEMM (16x16x32) + fused epilogue -
// block = 512 thr / 8 waves = (y-row yy, o-half nh); tile = 4y x 64x x 32o x 1z.
// Stage once per block: 72 full-wave glds (wave wv: q=wv&3, 9 rows) + 144 tail.
__global__ __launch_bounds__(512, 4) void conv_volterra_kernel(
    const u16* __restrict__ xlq, const u16* __restrict__ wb,
    const float* __restrict__ x, float* __restrict__ out) {
  __shared__ __align__(16) u16 tile[4 * QS];   // 78,400 B

  // XCD z-affinity: xcd = blk&7 owns z in [8*xcd, 8*xcd+8)
  int i = blockIdx.x;
  int xcd = i & 7, r = i >> 3;
  int z  = xcd * 8 + (r >> 5);
  int yt = (r >> 1) & 15;
  int b  = r & 1;
  int y0 = yt * 4;

  int tid = threadIdx.x, wv = tid >> 6, lane = tid & 63;
  int l15 = lane & 15, l4 = lane >> 4;
  int yy = wv >> 1, nh = wv & 1;

  // ---- stage: wave wv -> quarter q = wv&3, rows rr = 2k + (wv>>2) ----------
  {
    int sq = wv & 3, h = wv >> 2;
    const u16* gq = xlq + sq * PLANE;
    u16* ldsq = tile + sq * QS;
#pragma unroll
    for (int k = 0; k < 9; k++) {
      const int zs = k / 3, yrb = 2 * (k % 3);        // compile-time
      glds16(gq + XOFF(b, z + zs, y0 + yrb + h, 0) + lane * 8,
             ldsq + ((zs * 6 + yrb + h) * RS));
    }
  }
  // tail: x = 64,65 for all (q, row): 144 chunks
  if (tid < 144) {
    int q = tid & 3, u = tid >> 2;                    // u in [0,36)
    int rr = u >> 1, xt = 64 + (u & 1);
    int zs = rr / 6, yr = rr - zs * 6;
    u32x4 v = *(const u32x4*)(xlq + q * PLANE + XOFF(b, z + zs, y0 + yr, xt));
    *(u32x4*)(tile + q * QS + rr * RS + xt * 8) = v;
  }
  __syncthreads();

  f32x4 acc[3][4];
#pragma unroll
  for (int c = 0; c < 3; c++)
#pragma unroll
    for (int m = 0; m < 4; m++) acc[c][m] = (f32x4){0.f, 0.f, 0.f, 0.f};

  // A frag: voxel row = lane&15, k-quarter = lane>>4 (r1/r2/r4-verified)
  const u16* A0 = tile + (size_t)l4 * QS + (size_t)l15 * 8;
  const u16* wB = wb + nh * 512 + lane * 8;

#pragma unroll
  for (int kd = 0; kd < 3; ++kd)
#pragma unroll
    for (int khy = 0; khy < 3; ++khy) {
      const u16* Ar = A0 + (kd * 6 + yy + khy) * RS;
#pragma unroll
      for (int kw = 0; kw < 3; ++kw) {
        const int tap = (kd * 3 + khy) * 3 + kw;
        bf16x8 bwf[3];
#pragma unroll
        for (int c = 0; c < 3; c++)
          bwf[c] = *(const bf16x8*)(wB + (size_t)(tap * 3 + c) * 1024);
        bf16x8 a[4];
#pragma unroll
        for (int m = 0; m < 4; m++)
          a[m] = *(const bf16x8*)(Ar + (m * 16 + kw) * 8);
#pragma unroll
        for (int m = 0; m < 4; m++)
#pragma unroll
          for (int c = 0; c < 3; c++)
            acc[c][m] = __builtin_amdgcn_mfma_f32_16x16x32_bf16(
                a[m], bwf[c], acc[c][m], 0, 0, 0);
      }
    }

  // ---- fused epilogue: out = x * exp(l1 + l2*l3) ---------------------------
  const int o = nh * 16 + l15;
  const size_t pb = (size_t)(b * NCH + o) * D3 + ((size_t)z * DD + (y0 + yy)) * DD;
#pragma unroll
  for (int m = 0; m < 4; m++) {
    size_t idx = pb + m * 16 + l4 * 4;
    f32x4 xv = *(const f32x4*)(x + idx);
    f32x4 rr;
#pragma unroll
    for (int j = 0; j < 4; j++)
      rr[j] = xv[j] * __expf(acc[0][m][j] + acc[1][m][j] * acc[2][m][j]);
    *(f32x4*)(out + idx) = rr;
  }
}

extern "C" void kernel_launch(void* const* d_in, const int* in_sizes, int n_in,
                              void* d_out, int out_size, void* d_ws, size_t ws_size,
                              hipStream_t stream) {
  const float* x  = (const float*)d_in[0];
  const float* w1 = (const float*)d_in[1];
  const float* w2 = (const float*)d_in[2];
  const float* w3 = (const float*)d_in[3];
  float* out = (float*)d_out;
  u16* xlq = (u16*)d_ws;                               // 4 q-planes, 36.8 MB
  u16* wb  = xlq + 4 * PLANE;                          // +166 KB packed weights

  pack_w_kernel<<<(NTAP * 3 * 2 * 512 + 255) / 256, 256, 0, stream>>>(w1, w2, w3, wb);
  const int npad = BB * PD * PD * PD;
  zero_halo_kernel<<<(npad + 255) / 256, 256, 0, stream>>>(xlq);
  build_xl_kernel<<<BB * DD * 16, 256, 0, stream>>>(x, xlq);
  conv_volterra_kernel<<<2048, 512, 0, stream>>>(xlq, wb, x, out);
}